// Round 2
// baseline (303.462 us; speedup 1.0000x reference)
//
#include <hip/hip_runtime.h>
#include <math.h>

// ---------------------------------------------------------------------------
// YOLOv5 head: 1x1-conv decode + sigmoid + threshold + (top-k) + greedy NMS.
// Only the 3 obj channels are computed densely (one 42 MB read of f); the
// remaining 84 channels run only for the ~300 obj-passers (all on level 2
// with this init). R1 changes: L0 threshold fused into k1 (sole writer, no
// logits round-trip); k2 uses wave-cooperative rows with coalesced weight
// reads + shuffle reduction instead of per-lane K-striding (64-line scatter).
// ---------------------------------------------------------------------------

#define NUM_CLASSES 80
#define IMG_F 640.0f

// ws layout (units: 4-byte words)
#define LOGITS_F 0             // 48000 floats: L1/L2 split-K partials, [n][6000]
#define N_LOGITS 48000         //   n*6000 + (level==1 ? 0 : 4800) + s*3 + a
#define WPACK_F  48000         // 3584 floats: packed obj weights [c4][4]
#define N_WPACK  3584
#define CAND_F   (WPACK_F + N_WPACK)     // CAP1 x {code:int, obj:float}
#define CAP1     4096
#define CNT_F    (CAND_F + CAP1*2)       // [0]=cand count, [1..8]=per-image
#define IMGBUF_F (CNT_F + 16)            // 8 x CAP2 x 6 floats
#define CAP2     2048
// total = 59792 + 98304 = 158096 words ~= 632 KB of d_ws

#define LOGIT_T (-2.1972245773362196f)   // logit(0.1)

__constant__ float d_anch[3][3][2] = {
  {{6.1f,8.1f},{20.6f,12.6f},{11.2f,23.7f}},
  {{36.2f,26.8f},{25.9f,57.2f},{57.8f,47.9f}},
  {{122.1f,78.3f},{73.7f,143.8f},{236.1f,213.1f}},
};
__constant__ float d_stridec[3] = {8.f,16.f,32.f};

// ---------------------------------------------------------------- K0: init --
__global__ __launch_bounds__(256) void k0_init(
    float* __restrict__ ws, float* __restrict__ out,
    const float* __restrict__ w0, const float* __restrict__ w1,
    const float* __restrict__ w2) {
  int i = blockIdx.x * 256 + threadIdx.x;
  if (i < N_LOGITS) ws[LOGITS_F + i] = 0.f;
  if (i < 4800)     out[i] = 0.f;          // harness poisons d_out each call
  if (i < 16)       ((int*)ws)[CNT_F + i] = 0;
  if (i < N_WPACK) {
    // pack obj weight rows (o = a*85+4) into [c4][a] for float4 LDS broadcast
    int a = i & 3, c4 = i >> 2;            // c4: global float4 index 0..895
    float v = 0.f;
    if (a < 3) {
      if (c4 < 128)       v = w0[(a*85+4)*128 + c4];
      else if (c4 < 384)  v = w1[(a*85+4)*256 + (c4-128)];
      else                v = w2[(a*85+4)*512 + (c4-384)];
    }
    ws[WPACK_F + i] = v;
  }
}

// --------------------------------------------- K1: dense obj-logit GEMV ----
// 1 thread = 1 spatial position; 3 obj accumulators. L0 (K=128) is computed
// whole and thresholded inline (sole writer). L1/L2 split K across blocks
// (atomicAdd partials into the small logits buffer).
__global__ __launch_bounds__(256) void k1_obj(
    const float* __restrict__ f0, const float* __restrict__ f1,
    const float* __restrict__ f2, const float* __restrict__ b0,
    float* __restrict__ ws) {
  __shared__ float4 wl[128];
  int b = blockIdx.x, tid = threadIdx.x;
  int level, posblk, kc;
  if (b < 200)      { level = 0; posblk = b; kc = 0; }
  else if (b < 400) { int t = b - 200; level = 1; posblk = t % 50; kc = t / 50; }
  else              { int t = b - 400; level = 2; posblk = t % 13; kc = t / 13; }
  const int Cs[3]   = {128, 256, 512};
  const int HWs[3]  = {6400, 1600, 400};
  const int KBs[3]  = {1, 4, 8};
  const int W4B[3]  = {0, 128, 384};
  int C = Cs[level], HW = HWs[level], KB = KBs[level];
  int chunk = C / KB;                       // 128 / 64 / 64
  const float* f = (level == 0) ? f0 : (level == 1) ? f1 : f2;
  const float4* wp4 = (const float4*)(ws + WPACK_F);
  int c0 = kc * chunk;
  if (tid < chunk) wl[tid] = wp4[W4B[level] + c0 + tid];
  __syncthreads();
  int pos = posblk * 256 + tid;
  if (pos >= 8 * HW) return;
  int n = pos / HW, s = pos - n * HW;
  const float* fp = f + ((size_t)(n * C + c0)) * HW + s;
  float acc[3] = {0.f, 0.f, 0.f};
  #pragma unroll 16
  for (int c = 0; c < chunk; ++c) {
    float fv = fp[(size_t)c * HW];          // coalesced across lanes
    float4 w4 = wl[c];                      // LDS broadcast
    acc[0] = fmaf(fv, w4.x, acc[0]);
    acc[1] = fmaf(fv, w4.y, acc[1]);
    acc[2] = fmaf(fv, w4.z, acc[2]);
  }
  if (level == 0) {
    // sole writer: fuse bias + sigmoid threshold + candidate push
    #pragma unroll
    for (int a = 0; a < 3; ++a) {
      float logit = acc[a] + b0[a * 85 + 4];
      if (logit > LOGIT_T) {
        float obj = 1.f / (1.f + expf(-logit));
        int idx = atomicAdd((int*)ws + CNT_F, 1);
        if (idx < CAP1) {
          int* cd = (int*)ws + CAND_F + idx * 2;
          cd[0] = (n << 24) | (0 << 20) | (a << 16) | s;
          ((float*)cd)[1] = obj;
        }
      }
    }
  } else {
    float* lg = ws + LOGITS_F + n * 6000 + ((level == 1) ? 0 : 4800) + s * 3;
    atomicAdd(lg + 0, acc[0]);
    atomicAdd(lg + 1, acc[1]);
    atomicAdd(lg + 2, acc[2]);
  }
}

// ----------------------- K1b: L1/L2 bias + sigmoid threshold ---------------
__global__ __launch_bounds__(256) void k1b_thresh(
    float* __restrict__ ws, const float* __restrict__ b1,
    const float* __restrict__ b2) {
  int i = blockIdx.x * 256 + threadIdx.x;
  if (i >= N_LOGITS) return;
  int n = i / 6000, r = i - n * 6000;
  int level = (r < 4800) ? 1 : 2;
  int roff = (r < 4800) ? r : r - 4800;
  int s = roff / 3, a = roff - s * 3;
  const float* bb = (level == 1) ? b1 : b2;
  float logit = ws[LOGITS_F + i] + bb[a * 85 + 4];
  if (logit > LOGIT_T) {
    float obj = 1.f / (1.f + expf(-logit));
    int idx = atomicAdd((int*)ws + CNT_F, 1);
    if (idx < CAP1) {
      int* cd = (int*)ws + CAND_F + idx * 2;
      cd[0] = (n << 24) | (level << 20) | (a << 16) | s;
      ((float*)cd)[1] = obj;
    }
  }
}

// ------------- K2: per-candidate rows, wave-cooperative + coalesced --------
// One wave per candidate (persistent loop). Feature column staged in regs
// (lane j holds f[c=lane+64j]); weight rows read coalesced across lanes;
// per-row dot via 6-step butterfly reduction. No LDS.
__global__ __launch_bounds__(256) void k2_score(
    const float* __restrict__ f0, const float* __restrict__ f1,
    const float* __restrict__ f2,
    const float* __restrict__ w0, const float* __restrict__ w1,
    const float* __restrict__ w2,
    const float* __restrict__ b0, const float* __restrict__ b1,
    const float* __restrict__ b2, float* __restrict__ ws) {
  int wv = threadIdx.x >> 6, lane = threadIdx.x & 63;
  int count = min(((int*)ws)[CNT_F], CAP1);
  int nslots = gridDim.x * 4;
  for (int cid = blockIdx.x * 4 + wv; cid < count; cid += nslots) {
    int* cd = (int*)ws + CAND_F + cid * 2;
    int code = cd[0]; float obj = ((float*)cd)[1];
    int n = code >> 24, level = (code >> 20) & 15, a = (code >> 16) & 3, s = code & 0xFFFF;
    int C = 128, HW = 6400, Wd = 80;
    const float *f = f0, *w = w0, *bb = b0;
    if (level == 1)      { C = 256; HW = 1600; Wd = 40; f = f1; w = w1; bb = b1; }
    else if (level == 2) { C = 512; HW = 400;  Wd = 20; f = f2; w = w2; bb = b2; }
    int J = C >> 6;                          // 2 / 4 / 8
    float fc[8];
    for (int j = 0; j < J; ++j)
      fc[j] = f[((size_t)(n * C + lane + 64 * j)) * HW + s];
    // rows 0..3: box params
    float p03[4];
    #pragma unroll
    for (int l = 0; l < 4; ++l) {
      const float* wr = w + (size_t)(a * 85 + l) * C;
      float r = 0.f;
      for (int j = 0; j < J; ++j) r = fmaf(fc[j], wr[lane + 64 * j], r);
      #pragma unroll
      for (int m = 32; m; m >>= 1) r += __shfl_xor(r, m, 64);
      p03[l] = 1.f / (1.f + expf(-(r + bb[a * 85 + l])));
    }
    int gx = s % Wd, gy = s / Wd;
    float st = d_stridec[level];
    float cx = (2.f * p03[0] - 0.5f + (float)gx) * st;
    float cy = (2.f * p03[1] - 0.5f + (float)gy) * st;
    float bw = 4.f * p03[2] * p03[2] * d_anch[level][a][0];
    float bh = 4.f * p03[3] * p03[3] * d_anch[level][a][1];
    float x1 = fminf(fmaxf(cx - bw * 0.5f, 0.f), IMG_F);
    float y1 = fminf(fmaxf(cy - bh * 0.5f, 0.f), IMG_F);
    float x2 = fminf(fmaxf(cx + bw * 0.5f, 0.f), IMG_F);
    float y2 = fminf(fmaxf(cy + bh * 0.5f, 0.f), IMG_F);
    // rows 5..84: class scores
    for (int l = 5; l < 85; ++l) {
      const float* wr = w + (size_t)(a * 85 + l) * C;
      float r = 0.f;
      for (int j = 0; j < J; ++j) r = fmaf(fc[j], wr[lane + 64 * j], r);
      #pragma unroll
      for (int m = 32; m; m >>= 1) r += __shfl_xor(r, m, 64);
      float cls = 1.f / (1.f + expf(-(r + bb[a * 85 + l])));
      float sc = obj * cls;
      if (sc > 0.1f && lane == 0) {
        int p = atomicAdd((int*)ws + CNT_F + 1 + n, 1);
        if (p < CAP2) {
          float* dst = ws + IMGBUF_F + ((size_t)(n * CAP2 + p)) * 6;
          dst[0] = x1; dst[1] = y1; dst[2] = x2; dst[3] = y2;
          dst[4] = sc; dst[5] = (float)(l - 5);
        }
      }
    }
  }
}

// ------------------------------------------ K3: per-image greedy NMS -------
__global__ __launch_bounds__(256) void k3_nms(
    const float* __restrict__ ws, float* __restrict__ out,
    const float* __restrict__ sfp) {
  __shared__ float bx1[CAP2], by1[CAP2], bx2[CAP2], by2[CAP2], bsc[CAP2], blb[CAP2];
  __shared__ int bval[CAP2];
  __shared__ float rs[256];
  __shared__ int ri[256];
  int n = blockIdx.x, tid = threadIdx.x;
  int cnt = min(((const int*)ws)[CNT_F + 1 + n], CAP2);
  for (int i = tid; i < cnt; i += 256) {
    const float* src = ws + IMGBUF_F + ((size_t)(n * CAP2 + i)) * 6;
    bx1[i] = src[0]; by1[i] = src[1]; bx2[i] = src[2]; by2[i] = src[3];
    bsc[i] = src[4]; blb[i] = src[5]; bval[i] = 1;
  }
  __syncthreads();
  float sf = sfp[n];
  for (int it = 0; it < 100; ++it) {
    float best = -1.f; int bi = -1;
    for (int i = tid; i < cnt; i += 256)
      if (bval[i] && bsc[i] > best) { best = bsc[i]; bi = i; }
    rs[tid] = best; ri[tid] = bi;
    __syncthreads();
    for (int off = 128; off > 0; off >>= 1) {
      if (tid < off && rs[tid + off] > rs[tid]) { rs[tid] = rs[tid + off]; ri[tid] = ri[tid + off]; }
      __syncthreads();
    }
    int wi = ri[0]; float wsc = rs[0];
    if (wi < 0) break;                      // uniform: no valid left, rows stay 0
    if (tid == 0) {
      float* o = out + (size_t)(n * 100 + it) * 6;
      o[0] = bx1[wi] / sf; o[1] = by1[wi] / sf;
      o[2] = bx2[wi] / sf; o[3] = by2[wi] / sf;
      o[4] = wsc;          o[5] = blb[wi];
    }
    // suppress IoU > 0.6 on class-offset boxes (offset adds to all 4 coords)
    float ofw = blb[wi] * IMG_F;
    float wx1 = bx1[wi] + ofw, wy1 = by1[wi] + ofw;
    float wx2 = bx2[wi] + ofw, wy2 = by2[wi] + ofw;
    float wa = (wx2 - wx1) * (wy2 - wy1);
    for (int i = tid; i < cnt; i += 256) {
      if (bval[i]) {
        float o2 = blb[i] * IMG_F;
        float x1 = bx1[i] + o2, y1 = by1[i] + o2, x2 = bx2[i] + o2, y2 = by2[i] + o2;
        float iw = fmaxf(fminf(wx2, x2) - fmaxf(wx1, x1), 0.f);
        float ih = fmaxf(fminf(wy2, y2) - fmaxf(wy1, y1), 0.f);
        float inter = iw * ih;
        float area = (x2 - x1) * (y2 - y1);
        float iou = inter / (wa + area - inter + 1e-7f);
        if (iou > 0.6f) bval[i] = 0;
      }
    }
    if (tid == 0) bval[wi] = 0;
    __syncthreads();
  }
}

// ---------------------------------------------------------------------------
extern "C" void kernel_launch(void* const* d_in, const int* in_sizes, int n_in,
                              void* d_out, int out_size, void* d_ws, size_t ws_size,
                              hipStream_t stream) {
  // setup_inputs() dict order: f0,w0,b0, f1,w1,b1, f2,w2,b2, scale_factors
  const float* f0 = (const float*)d_in[0];
  const float* w0 = (const float*)d_in[1];
  const float* b0 = (const float*)d_in[2];
  const float* f1 = (const float*)d_in[3];
  const float* w1 = (const float*)d_in[4];
  const float* b1 = (const float*)d_in[5];
  const float* f2 = (const float*)d_in[6];
  const float* w2 = (const float*)d_in[7];
  const float* b2 = (const float*)d_in[8];
  const float* sf = (const float*)d_in[9];
  float* out = (float*)d_out;
  float* ws  = (float*)d_ws;    // needs ~632 KB

  k0_init   <<<188, 256, 0, stream>>>(ws, out, w0, w1, w2);
  k1_obj    <<<504, 256, 0, stream>>>(f0, f1, f2, b0, ws);
  k1b_thresh<<<188, 256, 0, stream>>>(ws, b1, b2);
  k2_score  <<<140, 256, 0, stream>>>(f0, f1, f2, w0, w1, w2, b0, b1, b2, ws);
  k3_nms    <<<8, 256, 0, stream>>>(ws, out, sf);
}

// Round 3
// 134.900 us; speedup vs baseline: 2.2495x; 2.2495x over previous
//
#include <hip/hip_runtime.h>
#include <math.h>

// ---------------------------------------------------------------------------
// YOLOv5 head: 1x1-conv decode + sigmoid + threshold + (top-k) + greedy NMS.
// Only the 3 obj channels are computed densely (one 42 MB read of f); the
// remaining 84 channels run only for the ~300 obj-passers. R3: k2 rebuilt —
// R2's runtime-indexed fc[8] spilled to scratch (VGPR_Count=28!) and each row
// ended in a 6-deep dependent shuffle chain => 250 us pure-latency kernel.
// Now: k0 packs weights transposed wT[level][a][c][128] (rows innermost,
// zero-padded), k2 assigns lane=row, inner loop over c reads LDS-broadcast
// f[c] * coalesced wT[c][lane]. No shuffles in the loop, no scratch,
// constexpr trip counts via template<int C>.
// ---------------------------------------------------------------------------

#define NUM_CLASSES 80
#define IMG_F 640.0f

// ws layout (units: 4-byte words)
#define LOGITS_F 0             // 48000 floats: L1/L2 split-K partials, [n][6000]
#define N_LOGITS 48000         //   n*6000 + (level==1 ? 0 : 4800) + s*3 + a
#define WPACK_F  48000         // 3584 floats: packed obj weights [c4][4]
#define N_WPACK  3584
#define WT_F     (WPACK_F + N_WPACK)     // 51584: transposed weights
#define N_WT     344064        // [level][a][c][128], l innermost, pad l>=85 = 0
#define WT_L0    0             // 3*128*128 = 49152
#define WT_L1    49152         // 3*256*128 = 98304
#define WT_L2    147456        // 3*512*128 = 196608
#define CAND_F   (WT_F + N_WT)           // 395648: CAP1 x {code:int, obj:float}
#define CAP1     4096
#define CNT_F    (CAND_F + CAP1*2)       // 403840: [0]=cand count, [1..8]=/img
#define IMGBUF_F (CNT_F + 16)            // 403856: 8 x CAP2 x 6 floats
#define CAP2     2048
// total = 502160 words ~= 2.0 MB of d_ws

#define LOGIT_T (-2.1972245773362196f)   // logit(0.1)

__constant__ float d_anch[3][3][2] = {
  {{6.1f,8.1f},{20.6f,12.6f},{11.2f,23.7f}},
  {{36.2f,26.8f},{25.9f,57.2f},{57.8f,47.9f}},
  {{122.1f,78.3f},{73.7f,143.8f},{236.1f,213.1f}},
};
__constant__ float d_stridec[3] = {8.f,16.f,32.f};

// ---------------------------------------------------------------- K0: init --
__global__ __launch_bounds__(256) void k0_init(
    float* __restrict__ ws, float* __restrict__ out,
    const float* __restrict__ w0, const float* __restrict__ w1,
    const float* __restrict__ w2) {
  int i = blockIdx.x * 256 + threadIdx.x;
  if (i < N_LOGITS) ws[LOGITS_F + i] = 0.f;
  if (i < 4800)     out[i] = 0.f;          // harness poisons d_out each call
  if (i < 16)       ((int*)ws)[CNT_F + i] = 0;
  if (i < N_WPACK) {
    // pack obj weight rows (o = a*85+4) into [c4][a] for float4 LDS broadcast
    int a = i & 3, c4 = i >> 2;            // c4: global float4 index 0..895
    float v = 0.f;
    if (a < 3) {
      if (c4 < 128)       v = w0[(a*85+4)*128 + c4];
      else if (c4 < 384)  v = w1[(a*85+4)*256 + (c4-128)];
      else                v = w2[(a*85+4)*512 + (c4-384)];
    }
    ws[WPACK_F + i] = v;
  }
  if (i < N_WT) {
    // transposed weights: wT[level][a][c][128], row l innermost, pad -> 0.
    // writes coalesced (l fastest); scattered reads absorbed by L2 (~1 MB).
    int level, C, i2;
    const float* w;
    if (i < WT_L1)          { level = 0; C = 128; i2 = i;            w = w0; }
    else if (i < WT_L2)     { level = 1; C = 256; i2 = i - WT_L1;    w = w1; }
    else                    { level = 2; C = 512; i2 = i - WT_L2;    w = w2; }
    int a = i2 / (C * 128);
    int r = i2 - a * (C * 128);
    int c = r >> 7, l = r & 127;
    ws[WT_F + i] = (l < 85) ? w[(size_t)(a * 85 + l) * C + c] : 0.f;
    (void)level;
  }
}

// --------------------------------------------- K1: dense obj-logit GEMV ----
// 1 thread = 1 spatial position; 3 obj accumulators. L0 (K=128) is computed
// whole and thresholded inline (sole writer). L1/L2 split K across blocks
// (atomicAdd partials into the small logits buffer).
__global__ __launch_bounds__(256) void k1_obj(
    const float* __restrict__ f0, const float* __restrict__ f1,
    const float* __restrict__ f2, const float* __restrict__ b0,
    float* __restrict__ ws) {
  __shared__ float4 wl[128];
  int b = blockIdx.x, tid = threadIdx.x;
  int level, posblk, kc;
  if (b < 200)      { level = 0; posblk = b; kc = 0; }
  else if (b < 400) { int t = b - 200; level = 1; posblk = t % 50; kc = t / 50; }
  else              { int t = b - 400; level = 2; posblk = t % 13; kc = t / 13; }
  const int Cs[3]   = {128, 256, 512};
  const int HWs[3]  = {6400, 1600, 400};
  const int KBs[3]  = {1, 4, 8};
  const int W4B[3]  = {0, 128, 384};
  int C = Cs[level], HW = HWs[level], KB = KBs[level];
  int chunk = C / KB;                       // 128 / 64 / 64
  const float* f = (level == 0) ? f0 : (level == 1) ? f1 : f2;
  const float4* wp4 = (const float4*)(ws + WPACK_F);
  int c0 = kc * chunk;
  if (tid < chunk) wl[tid] = wp4[W4B[level] + c0 + tid];
  __syncthreads();
  int pos = posblk * 256 + tid;
  if (pos >= 8 * HW) return;
  int n = pos / HW, s = pos - n * HW;
  const float* fp = f + ((size_t)(n * C + c0)) * HW + s;
  float acc[3] = {0.f, 0.f, 0.f};
  #pragma unroll 16
  for (int c = 0; c < chunk; ++c) {
    float fv = fp[(size_t)c * HW];          // coalesced across lanes
    float4 w4 = wl[c];                      // LDS broadcast
    acc[0] = fmaf(fv, w4.x, acc[0]);
    acc[1] = fmaf(fv, w4.y, acc[1]);
    acc[2] = fmaf(fv, w4.z, acc[2]);
  }
  if (level == 0) {
    // sole writer: fuse bias + sigmoid threshold + candidate push
    #pragma unroll
    for (int a = 0; a < 3; ++a) {
      float logit = acc[a] + b0[a * 85 + 4];
      if (logit > LOGIT_T) {
        float obj = 1.f / (1.f + expf(-logit));
        int idx = atomicAdd((int*)ws + CNT_F, 1);
        if (idx < CAP1) {
          int* cd = (int*)ws + CAND_F + idx * 2;
          cd[0] = (n << 24) | (0 << 20) | (a << 16) | s;
          ((float*)cd)[1] = obj;
        }
      }
    }
  } else {
    float* lg = ws + LOGITS_F + n * 6000 + ((level == 1) ? 0 : 4800) + s * 3;
    atomicAdd(lg + 0, acc[0]);
    atomicAdd(lg + 1, acc[1]);
    atomicAdd(lg + 2, acc[2]);
  }
}

// ----------------------- K1b: L1/L2 bias + sigmoid threshold ---------------
__global__ __launch_bounds__(256) void k1b_thresh(
    float* __restrict__ ws, const float* __restrict__ b1,
    const float* __restrict__ b2) {
  int i = blockIdx.x * 256 + threadIdx.x;
  if (i >= N_LOGITS) return;
  int n = i / 6000, r = i - n * 6000;
  int level = (r < 4800) ? 1 : 2;
  int roff = (r < 4800) ? r : r - 4800;
  int s = roff / 3, a = roff - s * 3;
  const float* bb = (level == 1) ? b1 : b2;
  float logit = ws[LOGITS_F + i] + bb[a * 85 + 4];
  if (logit > LOGIT_T) {
    float obj = 1.f / (1.f + expf(-logit));
    int idx = atomicAdd((int*)ws + CNT_F, 1);
    if (idx < CAP1) {
      int* cd = (int*)ws + CAND_F + idx * 2;
      cd[0] = (n << 24) | (level << 20) | (a << 16) | s;
      ((float*)cd)[1] = obj;
    }
  }
}

// -------- K2: one wave per candidate, lane = output row, coalesced wT ------
template<int C, int HW, int Wd>
__device__ __forceinline__ void k2_cand(
    int level, int n, int a, int s, float obj,
    const float* __restrict__ f, const float* __restrict__ wTl,
    const float* __restrict__ bb, float* __restrict__ ws,
    float* __restrict__ fc /* this wave's 512-float LDS slab */, int lane) {
  // stage feature column (scattered: stride-HW gather, C/64 instrs)
  #pragma unroll
  for (int j = 0; j < C / 64; ++j)
    fc[lane + 64 * j] = f[((size_t)(n * C + lane + 64 * j)) * HW + s];
  const float* wA = wTl + (size_t)a * C * 128;
  float acc1 = 0.f, acc2 = 0.f;          // rows: lane, 64+lane (pad rows = 0)
  #pragma unroll 8
  for (int c = 0; c < C; ++c) {
    float fv = fc[c];                    // LDS broadcast, conflict-free
    const float* wl = wA + c * 128;
    acc1 = fmaf(fv, wl[lane], acc1);     // coalesced 64 consecutive floats
    acc2 = fmaf(fv, wl[64 + lane], acc2);
  }
  acc1 += bb[a * 85 + lane];             // rows 0..63 all valid
  float sig1 = 1.f / (1.f + expf(-acc1));
  float sig2 = 0.f;
  if (lane < 21) {                       // rows 64..84
    acc2 += bb[a * 85 + 64 + lane];
    sig2 = 1.f / (1.f + expf(-acc2));
  }
  // box from rows 0..3
  float p0 = __shfl(sig1, 0, 64), p1 = __shfl(sig1, 1, 64);
  float p2 = __shfl(sig1, 2, 64), p3 = __shfl(sig1, 3, 64);
  int gx = s % Wd, gy = s / Wd;
  float st = d_stridec[level];
  float cx = (2.f * p0 - 0.5f + (float)gx) * st;
  float cy = (2.f * p1 - 0.5f + (float)gy) * st;
  float bw = 4.f * p2 * p2 * d_anch[level][a][0];
  float bh = 4.f * p3 * p3 * d_anch[level][a][1];
  float x1 = fminf(fmaxf(cx - bw * 0.5f, 0.f), IMG_F);
  float y1 = fminf(fmaxf(cy - bh * 0.5f, 0.f), IMG_F);
  float x2 = fminf(fmaxf(cx + bw * 0.5f, 0.f), IMG_F);
  float y2 = fminf(fmaxf(cy + bh * 0.5f, 0.f), IMG_F);
  // class scores: row lane (lane>=5 -> class lane-5), row 64+lane (class 59+lane)
  #pragma unroll
  for (int half = 0; half < 2; ++half) {
    bool on = half == 0 ? (lane >= 5) : (lane < 21);
    float sc = obj * (half == 0 ? sig1 : sig2);
    int cls = half == 0 ? (lane - 5) : (59 + lane);
    if (on && sc > 0.1f) {
      int p = atomicAdd((int*)ws + CNT_F + 1 + n, 1);
      if (p < CAP2) {
        float* dst = ws + IMGBUF_F + ((size_t)(n * CAP2 + p)) * 6;
        dst[0] = x1; dst[1] = y1; dst[2] = x2; dst[3] = y2;
        dst[4] = sc; dst[5] = (float)cls;
      }
    }
  }
}

__global__ __launch_bounds__(256) void k2_score(
    const float* __restrict__ f0, const float* __restrict__ f1,
    const float* __restrict__ f2,
    const float* __restrict__ b0, const float* __restrict__ b1,
    const float* __restrict__ b2, float* __restrict__ ws) {
  __shared__ float fcol[4][512];
  int wv = threadIdx.x >> 6, lane = threadIdx.x & 63;
  int count = min(((int*)ws)[CNT_F], CAP1);
  int nslots = gridDim.x * 4;
  for (int cid = blockIdx.x * 4 + wv; cid < count; cid += nslots) {
    int* cd = (int*)ws + CAND_F + cid * 2;
    int code = cd[0]; float obj = ((float*)cd)[1];
    int n = code >> 24, level = (code >> 20) & 15, a = (code >> 16) & 3, s = code & 0xFFFF;
    if (level == 0)
      k2_cand<128, 6400, 80>(0, n, a, s, obj, f0, ws + WT_F + WT_L0, b0, ws, fcol[wv], lane);
    else if (level == 1)
      k2_cand<256, 1600, 40>(1, n, a, s, obj, f1, ws + WT_F + WT_L1, b1, ws, fcol[wv], lane);
    else
      k2_cand<512, 400, 20>(2, n, a, s, obj, f2, ws + WT_F + WT_L2, b2, ws, fcol[wv], lane);
  }
}

// ------------------------------------------ K3: per-image greedy NMS -------
__global__ __launch_bounds__(256) void k3_nms(
    const float* __restrict__ ws, float* __restrict__ out,
    const float* __restrict__ sfp) {
  __shared__ float bx1[CAP2], by1[CAP2], bx2[CAP2], by2[CAP2], bsc[CAP2], blb[CAP2];
  __shared__ int bval[CAP2];
  __shared__ float rs[256];
  __shared__ int ri[256];
  int n = blockIdx.x, tid = threadIdx.x;
  int cnt = min(((const int*)ws)[CNT_F + 1 + n], CAP2);
  for (int i = tid; i < cnt; i += 256) {
    const float* src = ws + IMGBUF_F + ((size_t)(n * CAP2 + i)) * 6;
    bx1[i] = src[0]; by1[i] = src[1]; bx2[i] = src[2]; by2[i] = src[3];
    bsc[i] = src[4]; blb[i] = src[5]; bval[i] = 1;
  }
  __syncthreads();
  float sf = sfp[n];
  for (int it = 0; it < 100; ++it) {
    float best = -1.f; int bi = -1;
    for (int i = tid; i < cnt; i += 256)
      if (bval[i] && bsc[i] > best) { best = bsc[i]; bi = i; }
    rs[tid] = best; ri[tid] = bi;
    __syncthreads();
    for (int off = 128; off > 0; off >>= 1) {
      if (tid < off && rs[tid + off] > rs[tid]) { rs[tid] = rs[tid + off]; ri[tid] = ri[tid + off]; }
      __syncthreads();
    }
    int wi = ri[0]; float wsc = rs[0];
    if (wi < 0) break;                      // uniform: no valid left, rows stay 0
    if (tid == 0) {
      float* o = out + (size_t)(n * 100 + it) * 6;
      o[0] = bx1[wi] / sf; o[1] = by1[wi] / sf;
      o[2] = bx2[wi] / sf; o[3] = by2[wi] / sf;
      o[4] = wsc;          o[5] = blb[wi];
    }
    // suppress IoU > 0.6 on class-offset boxes (offset adds to all 4 coords)
    float ofw = blb[wi] * IMG_F;
    float wx1 = bx1[wi] + ofw, wy1 = by1[wi] + ofw;
    float wx2 = bx2[wi] + ofw, wy2 = by2[wi] + ofw;
    float wa = (wx2 - wx1) * (wy2 - wy1);
    for (int i = tid; i < cnt; i += 256) {
      if (bval[i]) {
        float o2 = blb[i] * IMG_F;
        float x1 = bx1[i] + o2, y1 = by1[i] + o2, x2 = bx2[i] + o2, y2 = by2[i] + o2;
        float iw = fmaxf(fminf(wx2, x2) - fmaxf(wx1, x1), 0.f);
        float ih = fmaxf(fminf(wy2, y2) - fmaxf(wy1, y1), 0.f);
        float inter = iw * ih;
        float area = (x2 - x1) * (y2 - y1);
        float iou = inter / (wa + area - inter + 1e-7f);
        if (iou > 0.6f) bval[i] = 0;
      }
    }
    if (tid == 0) bval[wi] = 0;
    __syncthreads();
  }
}

// ---------------------------------------------------------------------------
extern "C" void kernel_launch(void* const* d_in, const int* in_sizes, int n_in,
                              void* d_out, int out_size, void* d_ws, size_t ws_size,
                              hipStream_t stream) {
  // setup_inputs() dict order: f0,w0,b0, f1,w1,b1, f2,w2,b2, scale_factors
  const float* f0 = (const float*)d_in[0];
  const float* w0 = (const float*)d_in[1];
  const float* b0 = (const float*)d_in[2];
  const float* f1 = (const float*)d_in[3];
  const float* w1 = (const float*)d_in[4];
  const float* b1 = (const float*)d_in[5];
  const float* f2 = (const float*)d_in[6];
  const float* w2 = (const float*)d_in[7];
  const float* b2 = (const float*)d_in[8];
  const float* sf = (const float*)d_in[9];
  float* out = (float*)d_out;
  float* ws  = (float*)d_ws;    // needs ~2.0 MB

  k0_init   <<<1344, 256, 0, stream>>>(ws, out, w0, w1, w2);
  k1_obj    <<<504, 256, 0, stream>>>(f0, f1, f2, b0, ws);
  k1b_thresh<<<188, 256, 0, stream>>>(ws, b1, b2);
  k2_score  <<<128, 256, 0, stream>>>(f0, f1, f2, b0, b1, b2, ws);
  k3_nms    <<<8, 256, 0, stream>>>(ws, out, sf);
}